// Round 13
// baseline (239.912 us; speedup 1.0000x reference)
//
#include <hip/hip_runtime.h>
#include <hip/hip_bf16.h>

// Problem constants
#define NN 50000      // nodes
#define NE 800000     // edges
#define FD 4          // features
#define TD 12         // timesteps
#define CD 32         // channels
#define HD 12         // horizon
#define FT 48         // FD*TD
#define NBANK 8       // banks (contention reduction)

// Workspace layout (4-byte element offsets)
#define OFF_HEAD   0                    // int[NBANK*NN]   chain heads
#define OFF_DEG8   400000               // float[NBANK*NN] banked weighted degree
#define OFF_PAY    800000               // int4[NE] (row, w_bits, next, 0)
#define OFF_DIS    4000000              // float[NN]
#define OFF_XS     4050000              // float[NN*FT]  xs = dis[i]*x[i,:]
#define OFF_CST    6450000              // float[512]
// cst block: Az[128] @0, cz[32] @128, Ah[128] @160, ch[32] @288, probs[12] @320

// ---------------------------------------------------------------------------
// build: per edge: banked atomicExch chain insert + banked f32 atomicAdd of
// weighted degree + one coalesced 16B payload write (row, w, next).
// head pre-set to -1 (memset 0xFF); deg8 pre-set to 0 (memset 0).
// Extra block computes the fused tiny matrices:
// (H0 stays zero in the reference => R-gate dead; only top 32 rows of Wl*
//  matter:  Az = Wz@Wlz[0:32,:],  cz = blz + bz@Wlz[0:32,:],  same for h.)
// ---------------------------------------------------------------------------
__global__ void build_pre_kernel(const int* __restrict__ ei, const float* __restrict__ w,
                                 int* __restrict__ head, float* __restrict__ deg8,
                                 int4* __restrict__ pay4,
                                 const float* __restrict__ Wz, const float* __restrict__ bz,
                                 const float* __restrict__ Wlz, const float* __restrict__ blz,
                                 const float* __restrict__ Wh, const float* __restrict__ bh,
                                 const float* __restrict__ Wlh, const float* __restrict__ blh,
                                 const float* __restrict__ attention,
                                 float* __restrict__ cst) {
    int tid = threadIdx.x;
    if (blockIdx.x < (NE / 256)) {          // 3125 blocks cover NE exactly
        int e = blockIdx.x * 256 + tid;
        int r = ei[e];
        int c = ei[NE + e];
        float we = w[e];
        int bank = (e & (NBANK-1)) * NN + c;
        int old = atomicExch(&head[bank], e);
        atomicAdd(&deg8[bank], we);
        pay4[e] = make_int4(r, __float_as_int(we), old, 0);
        return;
    }
    // one extra block: precompute cst
    if (tid < 128) {
        int f = tid >> 5, c = tid & 31;
        float s = 0.f, s2 = 0.f;
        #pragma unroll
        for (int k = 0; k < 32; ++k) {
            s  += Wz[f*32 + k] * Wlz[k*32 + c];
            s2 += Wh[f*32 + k] * Wlh[k*32 + c];
        }
        cst[tid]       = s;   // Az
        cst[160 + tid] = s2;  // Ah
    } else if (tid < 160) {
        int c = tid - 128;
        float s = blz[c], s2 = blh[c];
        #pragma unroll
        for (int k = 0; k < 32; ++k) {
            s  += bz[k] * Wlz[k*32 + c];
            s2 += bh[k] * Wlh[k*32 + c];
        }
        cst[128 + c] = s;   // cz
        cst[288 + c] = s2;  // ch
    } else if (tid == 160) {
        float m = -1e30f;
        for (int t = 0; t < TD; ++t) m = fmaxf(m, attention[t]);
        float e[TD], s = 0.f;
        #pragma unroll
        for (int t = 0; t < TD; ++t) { e[t] = __expf(attention[t] - m); s += e[t]; }
        float inv = 1.f / s;
        #pragma unroll
        for (int t = 0; t < TD; ++t) cst[320 + t] = e[t] * inv;
    }
}

// dis = rsqrt(sum_banks deg8 + 1); xs[i,:] = dis[i] * x[i,:]
// 16 lanes per node: lanes 0..7 load one bank each, xor-reduce, broadcast.
__global__ void disxs_kernel(const float* __restrict__ deg8, const float* __restrict__ x,
                             float* __restrict__ dis, float* __restrict__ xs) {
    int t = blockIdx.x * blockDim.x + threadIdx.x;   // NN*16 = 800000 exactly
    int i = t >> 4;
    int g = t & 15;
    float v = (g < 8) ? deg8[g * NN + i] : 0.f;
    v += __shfl_xor(v, 1, 8);
    v += __shfl_xor(v, 2, 8);
    v += __shfl_xor(v, 4, 8);
    float dsum = __shfl(v, 0, 16);
    float di = rsqrtf(dsum + 1.0f);
    if (g == 0) dis[i] = di;
    const float3* x3 = (const float3*)x;
    float3 xv = x3[i * 16 + g];
    ((float3*)xs)[i * 16 + g] = make_float3(di * xv.x, di * xv.y, di * xv.z);
}

// ---------------------------------------------------------------------------
// Fused gather + GRU + output. 16 lanes/node, 16 nodes/block.
// Per round: lanes 0..7 stash up to 8 chain edges each (STEP = single
// dependent 16B pay4 load — dis folded into xs), shfl-scan counts, write a
// COMPACTED (row, w) list to LDS, then ALL 16 lanes run a uniform-trip
// unroll-8 gather over xs: y[i] = dis[i] * (xs[i] + sum_e w_e * xs[row_e]).
// Phase B: GRU from LDS y. Phase C: output matvec.
// ---------------------------------------------------------------------------
__global__ __launch_bounds__(256) void gather_gru_kernel(
        const float* __restrict__ xs, const float* __restrict__ dis,
        const int* __restrict__ head, const int4* __restrict__ pay4,
        const float* __restrict__ cst, const float* __restrict__ Wout,
        const float* __restrict__ bout, float* __restrict__ out) {
    __shared__ int2  smeta[16][64];      // compacted (row, w) per node round
    __shared__ float sy[16][FT];
    __shared__ float hbuf[16][CD];
    __shared__ float sAz[128], sAh[128], sCz[32], sCh[32], sP[TD];
    __shared__ float sWout[CD * HD], sBout[HD];

    int tid = threadIdx.x;
    if (tid < 128) { sAz[tid] = cst[tid]; sAh[tid] = cst[160 + tid]; }
    if (tid < 32)  { sCz[tid] = cst[128 + tid]; sCh[tid] = cst[288 + tid]; }
    if (tid < TD)  { sP[tid] = cst[320 + tid]; sBout[tid] = bout[tid]; }
    for (int k = tid; k < CD * HD; k += 256) sWout[k] = Wout[k];
    __syncthreads();

    int g  = tid & 15;            // lane within node group
    int ln = tid >> 4;            // local node 0..15
    int i  = blockIdx.x * 16 + ln;

    const float3* xs3 = (const float3*)xs;   // 16 float3 per row
    float d = dis[i];
    float3 a = xs3[i * 16 + g];              // self term (already dis-scaled)
    float ax = a.x, ay = a.y, az = a.z;      // acc starts with self

    int e = (g < 8) ? head[g * NN + i] : -1;

    while (true) {
        // ---- stash up to 8 edges per bank-lane (single dependent load each) ----
        int r0=0,r1=0,r2=0,r3=0,r4=0,r5=0,r6=0,r7=0;
        float n0=0,n1=0,n2=0,n3=0,n4=0,n5=0,n6=0,n7=0;
        int cnt = 0;
        #define STEP(RK,NK) if (e >= 0) { int4 p = pay4[e]; RK = p.x; \
            NK = __int_as_float(p.y); e = p.z; ++cnt; }
        STEP(r0,n0) STEP(r1,n1) STEP(r2,n2) STEP(r3,n3)
        STEP(r4,n4) STEP(r5,n5) STEP(r6,n6) STEP(r7,n7)
        #undef STEP

        // ---- exclusive scan of cnt over the 16-lane segment ----
        int incl = cnt;
        #pragma unroll
        for (int dd = 1; dd < 8; dd <<= 1) {
            int t2 = __shfl_up(incl, dd, 16);
            if (g >= dd) incl += t2;
        }
        int S = __shfl(incl, 7, 16);      // total staged this round
        if (S == 0) break;
        int off = incl - cnt;

        // ---- compacted write ----
        if (cnt > 0) smeta[ln][off + 0] = make_int2(r0, __float_as_int(n0));
        if (cnt > 1) smeta[ln][off + 1] = make_int2(r1, __float_as_int(n1));
        if (cnt > 2) smeta[ln][off + 2] = make_int2(r2, __float_as_int(n2));
        if (cnt > 3) smeta[ln][off + 3] = make_int2(r3, __float_as_int(n3));
        if (cnt > 4) smeta[ln][off + 4] = make_int2(r4, __float_as_int(n4));
        if (cnt > 5) smeta[ln][off + 5] = make_int2(r5, __float_as_int(n5));
        if (cnt > 6) smeta[ln][off + 6] = make_int2(r6, __float_as_int(n6));
        if (cnt > 7) smeta[ln][off + 7] = make_int2(r7, __float_as_int(n7));
        __builtin_amdgcn_wave_barrier();   // same-wave LDS RAW: keep order

        // ---- uniform gather over compacted list, all 16 lanes ----
        #pragma unroll 8
        for (int k = 0; k < S; ++k) {
            int2 m = smeta[ln][k];
            float nv = __int_as_float(m.y);
            float3 v = xs3[m.x * 16 + g];
            ax += nv * v.x; ay += nv * v.y; az += nv * v.z;
        }
    }

    sy[ln][g*3 + 0] = d * ax;
    sy[ln][g*3 + 1] = d * ay;
    sy[ln][g*3 + 2] = d * az;
    __syncthreads();

    // ---- Phase B: GRU, 2 channels per lane (c0=g, c1=g+16) ----
    {
        int c0 = g, c1 = g + 16;
        float az00 = sAz[c0], az01 = sAz[32+c0], az02 = sAz[64+c0], az03 = sAz[96+c0];
        float az10 = sAz[c1], az11 = sAz[32+c1], az12 = sAz[64+c1], az13 = sAz[96+c1];
        float ah00 = sAh[c0], ah01 = sAh[32+c0], ah02 = sAh[64+c0], ah03 = sAh[96+c0];
        float ah10 = sAh[c1], ah11 = sAh[32+c1], ah12 = sAh[64+c1], ah13 = sAh[96+c1];
        float cz0 = sCz[c0], cz1 = sCz[c1], ch0 = sCh[c0], ch1 = sCh[c1];

        float hacc0 = 0.f, hacc1 = 0.f;
        #pragma unroll
        for (int t = 0; t < TD; ++t) {
            float y0 = sy[ln][0*TD + t];
            float y1 = sy[ln][1*TD + t];
            float y2 = sy[ln][2*TD + t];
            float y3 = sy[ln][3*TD + t];
            float z0 = cz0 + y0*az00 + y1*az01 + y2*az02 + y3*az03;
            float z1 = cz1 + y0*az10 + y1*az11 + y2*az12 + y3*az13;
            float h0 = ch0 + y0*ah00 + y1*ah01 + y2*ah02 + y3*ah03;
            float h1 = ch1 + y0*ah10 + y1*ah11 + y2*ah12 + y3*ah13;
            float Z0 = 1.f / (1.f + __expf(-z0));
            float Z1 = 1.f / (1.f + __expf(-z1));
            float e0 = __expf(2.f * h0);
            float e1 = __expf(2.f * h1);
            float H0v = (e0 - 1.f) / (e0 + 1.f);
            float H1v = (e1 - 1.f) / (e1 + 1.f);
            float p = sP[t];
            hacc0 += p * (1.f - Z0) * H0v;
            hacc1 += p * (1.f - Z1) * H1v;
        }
        hbuf[ln][c0] = fmaxf(hacc0, 0.f);
        hbuf[ln][c1] = fmaxf(hacc1, 0.f);
    }
    __syncthreads();

    // ---- Phase C: out = relu(Hacc) @ Wout + bout ----
    if (tid < 16 * HD) {
        int lnode = tid / HD, hor = tid - lnode * HD;
        int gn = blockIdx.x * 16 + lnode;
        float s = sBout[hor];
        #pragma unroll
        for (int k = 0; k < CD; ++k) s += hbuf[lnode][k] * sWout[k * HD + hor];
        out[gn * HD + hor] = s;
    }
}

extern "C" void kernel_launch(void* const* d_in, const int* in_sizes, int n_in,
                              void* d_out, int out_size, void* d_ws, size_t ws_size,
                              hipStream_t stream) {
    const float* x      = (const float*)d_in[0];
    const int*   ei     = (const int*)d_in[1];    // int32, layout [rows..., cols...]
    const float* ew     = (const float*)d_in[2];
    const float* attn   = (const float*)d_in[3];
    const float* Wz     = (const float*)d_in[4];
    const float* bz     = (const float*)d_in[5];
    const float* Wlz    = (const float*)d_in[6];
    const float* blz    = (const float*)d_in[7];
    // d_in[8..11] = Wr, br, Wlr, blr — dead (H0 == 0 forever)
    const float* Wh     = (const float*)d_in[12];
    const float* bh     = (const float*)d_in[13];
    const float* Wlh    = (const float*)d_in[14];
    const float* blh    = (const float*)d_in[15];
    const float* Wout   = (const float*)d_in[16];
    const float* bout   = (const float*)d_in[17];
    float* out = (float*)d_out;

    float* ws   = (float*)d_ws;
    int*   head = (int*)(ws + OFF_HEAD);
    float* deg8 = ws + OFF_DEG8;
    int4*  pay4 = (int4*)(ws + OFF_PAY);
    float* dis  = ws + OFF_DIS;
    float* xs   = ws + OFF_XS;
    float* cst  = ws + OFF_CST;

    hipMemsetAsync(head, 0xFF, NBANK * NN * sizeof(int), stream);   // head = -1
    hipMemsetAsync(deg8, 0x00, NBANK * NN * sizeof(float), stream); // deg = 0

    build_pre_kernel<<<NE / 256 + 1, 256, 0, stream>>>(ei, ew, head, deg8, pay4,
                                                       Wz, bz, Wlz, blz,
                                                       Wh, bh, Wlh, blh, attn, cst);

    disxs_kernel<<<NN * 16 / 256, 256, 0, stream>>>(deg8, x, dis, xs);

    gather_gru_kernel<<<NN / 16, 256, 0, stream>>>(
        xs, dis, head, pay4, cst, Wout, bout, out);
}

// Round 15
// 199.393 us; speedup vs baseline: 1.2032x; 1.2032x over previous
//
#include <hip/hip_runtime.h>
#include <hip/hip_bf16.h>

// Problem constants
#define NN 50000      // nodes
#define NE 800000     // edges
#define FD 4          // features
#define TD 12         // timesteps
#define CD 32         // channels
#define HD 12         // horizon
#define FT 48         // FD*TD
#define NBANK 8       // chain banks per node

// Workspace layout (4-byte element offsets)
#define OFF_HEAD   0                    // int[NBANK*NN]   chain heads
#define OFF_PAY    400000               // int4[NE] (row, w_bits, next, 0)
#define OFF_DIS    3600000              // float[NN]
#define OFF_XS     3650000              // float[NN*FT]  xs = dis[i]*x[i,:]
#define OFF_CST    6050000              // float[512]
// cst block: Az[128] @0, cz[32] @128, Ah[128] @160, ch[32] @288, probs[12] @320

// ---------------------------------------------------------------------------
// build: per edge: ONE banked atomicExch chain insert + one coalesced 16B
// payload write (row, w, next). head pre-set to -1 (memset 0xFF).
// NO degree atomic here — round 13 showed 2 same-index atomics/edge costs
// +57us; degree is summed contention-free from the chains in degdis_xs.
// Extra block computes the fused tiny matrices:
// (H0 stays zero in the reference => R-gate dead; only top 32 rows of Wl*
//  matter:  Az = Wz@Wlz[0:32,:],  cz = blz + bz@Wlz[0:32,:],  same for h.)
// ---------------------------------------------------------------------------
__global__ void build_pre_kernel(const int* __restrict__ ei, const float* __restrict__ w,
                                 int* __restrict__ head, int4* __restrict__ pay4,
                                 const float* __restrict__ Wz, const float* __restrict__ bz,
                                 const float* __restrict__ Wlz, const float* __restrict__ blz,
                                 const float* __restrict__ Wh, const float* __restrict__ bh,
                                 const float* __restrict__ Wlh, const float* __restrict__ blh,
                                 const float* __restrict__ attention,
                                 float* __restrict__ cst) {
    int tid = threadIdx.x;
    if (blockIdx.x < (NE / 256)) {          // 3125 blocks cover NE exactly
        int e = blockIdx.x * 256 + tid;
        int r = ei[e];
        int c = ei[NE + e];
        int old = atomicExch(&head[(e & (NBANK-1)) * NN + c], e);
        pay4[e] = make_int4(r, __float_as_int(w[e]), old, 0);
        return;
    }
    // one extra block: precompute cst
    if (tid < 128) {
        int f = tid >> 5, c = tid & 31;
        float s = 0.f, s2 = 0.f;
        #pragma unroll
        for (int k = 0; k < 32; ++k) {
            s  += Wz[f*32 + k] * Wlz[k*32 + c];
            s2 += Wh[f*32 + k] * Wlh[k*32 + c];
        }
        cst[tid]       = s;   // Az
        cst[160 + tid] = s2;  // Ah
    } else if (tid < 160) {
        int c = tid - 128;
        float s = blz[c], s2 = blh[c];
        #pragma unroll
        for (int k = 0; k < 32; ++k) {
            s  += bz[k] * Wlz[k*32 + c];
            s2 += bh[k] * Wlh[k*32 + c];
        }
        cst[128 + c] = s;   // cz
        cst[288 + c] = s2;  // ch
    } else if (tid == 160) {
        float m = -1e30f;
        for (int t = 0; t < TD; ++t) m = fmaxf(m, attention[t]);
        float e[TD], s = 0.f;
        #pragma unroll
        for (int t = 0; t < TD; ++t) { e[t] = __expf(attention[t] - m); s += e[t]; }
        float inv = 1.f / s;
        #pragma unroll
        for (int t = 0; t < TD; ++t) cst[320 + t] = e[t] * inv;
    }
}

// Fused: weighted degree by chain walk (contention-free) -> dis -> xs scale.
// 16 lanes/node: lanes 0..7 walk one bank chain each (one 16B pay4 line per
// hop, dep-depth ~2), xor-reduce width 8, broadcast to 16, all lanes scale
// their float3 chunk of x into xs.
__global__ void degdis_xs_kernel(const int* __restrict__ head, const int4* __restrict__ pay4,
                                 const float* __restrict__ x, float* __restrict__ dis,
                                 float* __restrict__ xs) {
    int t = blockIdx.x * blockDim.x + threadIdx.x;   // NN*16 = 800000 exactly
    int i = t >> 4;
    int g = t & 15;
    float s = 0.f;
    if (g < 8) {
        int e = head[g * NN + i];
        while (e >= 0) {
            int4 p = pay4[e];
            s += __int_as_float(p.y);
            e = p.z;
        }
    }
    s += __shfl_xor(s, 1, 8);
    s += __shfl_xor(s, 2, 8);
    s += __shfl_xor(s, 4, 8);
    float dsum = __shfl(s, 0, 16);       // lane 0 of the 16-lane window
    float di = rsqrtf(dsum + 1.0f);
    if (g == 0) dis[i] = di;
    const float3* x3 = (const float3*)x;
    float3 xv = x3[i * 16 + g];
    ((float3*)xs)[i * 16 + g] = make_float3(di * xv.x, di * xv.y, di * xv.z);
}

// ---------------------------------------------------------------------------
// Fused gather + GRU + output. 16 lanes/node, 16 nodes/block.
// Per round: lanes 0..7 stash up to 8 chain edges each (STEP = single
// dependent 16B pay4 load — dis folded into xs), shfl-scan counts, write a
// COMPACTED (row, w) list to LDS, then ALL 16 lanes run a uniform-trip
// unroll-8 gather over xs: y[i] = dis[i] * (xs[i] + sum_e w_e * xs[row_e]).
// Phase B: GRU from LDS y. Phase C: output matvec.
// ---------------------------------------------------------------------------
__global__ __launch_bounds__(256) void gather_gru_kernel(
        const float* __restrict__ xs, const float* __restrict__ dis,
        const int* __restrict__ head, const int4* __restrict__ pay4,
        const float* __restrict__ cst, const float* __restrict__ Wout,
        const float* __restrict__ bout, float* __restrict__ out) {
    __shared__ int2  smeta[16][64];      // compacted (row, w) per node round
    __shared__ float sy[16][FT];
    __shared__ float hbuf[16][CD];
    __shared__ float sAz[128], sAh[128], sCz[32], sCh[32], sP[TD];
    __shared__ float sWout[CD * HD], sBout[HD];

    int tid = threadIdx.x;
    if (tid < 128) { sAz[tid] = cst[tid]; sAh[tid] = cst[160 + tid]; }
    if (tid < 32)  { sCz[tid] = cst[128 + tid]; sCh[tid] = cst[288 + tid]; }
    if (tid < TD)  { sP[tid] = cst[320 + tid]; sBout[tid] = bout[tid]; }
    for (int k = tid; k < CD * HD; k += 256) sWout[k] = Wout[k];
    __syncthreads();

    int g  = tid & 15;            // lane within node group
    int ln = tid >> 4;            // local node 0..15
    int i  = blockIdx.x * 16 + ln;

    const float3* xs3 = (const float3*)xs;   // 16 float3 per row
    float d = dis[i];
    float3 a = xs3[i * 16 + g];              // self term (already dis-scaled)
    float ax = a.x, ay = a.y, az = a.z;      // acc starts with self

    int e = (g < 8) ? head[g * NN + i] : -1;

    while (true) {
        // ---- stash up to 8 edges per bank-lane (single dependent load each) ----
        int r0=0,r1=0,r2=0,r3=0,r4=0,r5=0,r6=0,r7=0;
        float n0=0,n1=0,n2=0,n3=0,n4=0,n5=0,n6=0,n7=0;
        int cnt = 0;
        #define STEP(RK,NK) if (e >= 0) { int4 p = pay4[e]; RK = p.x; \
            NK = __int_as_float(p.y); e = p.z; ++cnt; }
        STEP(r0,n0) STEP(r1,n1) STEP(r2,n2) STEP(r3,n3)
        STEP(r4,n4) STEP(r5,n5) STEP(r6,n6) STEP(r7,n7)
        #undef STEP

        // ---- exclusive scan of cnt over the 16-lane segment ----
        int incl = cnt;
        #pragma unroll
        for (int dd = 1; dd < 8; dd <<= 1) {
            int t2 = __shfl_up(incl, dd, 16);
            if (g >= dd) incl += t2;
        }
        int S = __shfl(incl, 7, 16);      // total staged this round
        if (S == 0) break;
        int off = incl - cnt;

        // ---- compacted write ----
        if (cnt > 0) smeta[ln][off + 0] = make_int2(r0, __float_as_int(n0));
        if (cnt > 1) smeta[ln][off + 1] = make_int2(r1, __float_as_int(n1));
        if (cnt > 2) smeta[ln][off + 2] = make_int2(r2, __float_as_int(n2));
        if (cnt > 3) smeta[ln][off + 3] = make_int2(r3, __float_as_int(n3));
        if (cnt > 4) smeta[ln][off + 4] = make_int2(r4, __float_as_int(n4));
        if (cnt > 5) smeta[ln][off + 5] = make_int2(r5, __float_as_int(n5));
        if (cnt > 6) smeta[ln][off + 6] = make_int2(r6, __float_as_int(n6));
        if (cnt > 7) smeta[ln][off + 7] = make_int2(r7, __float_as_int(n7));
        __builtin_amdgcn_wave_barrier();   // same-wave LDS RAW: keep order

        // ---- uniform gather over compacted list, all 16 lanes ----
        #pragma unroll 8
        for (int k = 0; k < S; ++k) {
            int2 m = smeta[ln][k];
            float nv = __int_as_float(m.y);
            float3 v = xs3[m.x * 16 + g];
            ax += nv * v.x; ay += nv * v.y; az += nv * v.z;
        }
    }

    sy[ln][g*3 + 0] = d * ax;
    sy[ln][g*3 + 1] = d * ay;
    sy[ln][g*3 + 2] = d * az;
    __syncthreads();

    // ---- Phase B: GRU, 2 channels per lane (c0=g, c1=g+16) ----
    {
        int c0 = g, c1 = g + 16;
        float az00 = sAz[c0], az01 = sAz[32+c0], az02 = sAz[64+c0], az03 = sAz[96+c0];
        float az10 = sAz[c1], az11 = sAz[32+c1], az12 = sAz[64+c1], az13 = sAz[96+c1];
        float ah00 = sAh[c0], ah01 = sAh[32+c0], ah02 = sAh[64+c0], ah03 = sAh[96+c0];
        float ah10 = sAh[c1], ah11 = sAh[32+c1], ah12 = sAh[64+c1], ah13 = sAh[96+c1];
        float cz0 = sCz[c0], cz1 = sCz[c1], ch0 = sCh[c0], ch1 = sCh[c1];

        float hacc0 = 0.f, hacc1 = 0.f;
        #pragma unroll
        for (int t = 0; t < TD; ++t) {
            float y0 = sy[ln][0*TD + t];
            float y1 = sy[ln][1*TD + t];
            float y2 = sy[ln][2*TD + t];
            float y3 = sy[ln][3*TD + t];
            float z0 = cz0 + y0*az00 + y1*az01 + y2*az02 + y3*az03;
            float z1 = cz1 + y0*az10 + y1*az11 + y2*az12 + y3*az13;
            float h0 = ch0 + y0*ah00 + y1*ah01 + y2*ah02 + y3*ah03;
            float h1 = ch1 + y0*ah10 + y1*ah11 + y2*ah12 + y3*ah13;
            float Z0 = 1.f / (1.f + __expf(-z0));
            float Z1 = 1.f / (1.f + __expf(-z1));
            float e0 = __expf(2.f * h0);
            float e1 = __expf(2.f * h1);
            float H0v = (e0 - 1.f) / (e0 + 1.f);
            float H1v = (e1 - 1.f) / (e1 + 1.f);
            float p = sP[t];
            hacc0 += p * (1.f - Z0) * H0v;
            hacc1 += p * (1.f - Z1) * H1v;
        }
        hbuf[ln][c0] = fmaxf(hacc0, 0.f);
        hbuf[ln][c1] = fmaxf(hacc1, 0.f);
    }
    __syncthreads();

    // ---- Phase C: out = relu(Hacc) @ Wout + bout ----
    if (tid < 16 * HD) {
        int lnode = tid / HD, hor = tid - lnode * HD;
        int gn = blockIdx.x * 16 + lnode;
        float s = sBout[hor];
        #pragma unroll
        for (int k = 0; k < CD; ++k) s += hbuf[lnode][k] * sWout[k * HD + hor];
        out[gn * HD + hor] = s;
    }
}

extern "C" void kernel_launch(void* const* d_in, const int* in_sizes, int n_in,
                              void* d_out, int out_size, void* d_ws, size_t ws_size,
                              hipStream_t stream) {
    const float* x      = (const float*)d_in[0];
    const int*   ei     = (const int*)d_in[1];    // int32, layout [rows..., cols...]
    const float* ew     = (const float*)d_in[2];
    const float* attn   = (const float*)d_in[3];
    const float* Wz     = (const float*)d_in[4];
    const float* bz     = (const float*)d_in[5];
    const float* Wlz    = (const float*)d_in[6];
    const float* blz    = (const float*)d_in[7];
    // d_in[8..11] = Wr, br, Wlr, blr — dead (H0 == 0 forever)
    const float* Wh     = (const float*)d_in[12];
    const float* bh     = (const float*)d_in[13];
    const float* Wlh    = (const float*)d_in[14];
    const float* blh    = (const float*)d_in[15];
    const float* Wout   = (const float*)d_in[16];
    const float* bout   = (const float*)d_in[17];
    float* out = (float*)d_out;

    float* ws   = (float*)d_ws;
    int*   head = (int*)(ws + OFF_HEAD);
    int4*  pay4 = (int4*)(ws + OFF_PAY);
    float* dis  = ws + OFF_DIS;
    float* xs   = ws + OFF_XS;
    float* cst  = ws + OFF_CST;

    hipMemsetAsync(head, 0xFF, NBANK * NN * sizeof(int), stream);   // head = -1

    build_pre_kernel<<<NE / 256 + 1, 256, 0, stream>>>(ei, ew, head, pay4,
                                                       Wz, bz, Wlz, blz,
                                                       Wh, bh, Wlh, blh, attn, cst);

    degdis_xs_kernel<<<NN * 16 / 256, 256, 0, stream>>>(head, pay4, x, dis, xs);

    gather_gru_kernel<<<NN / 16, 256, 0, stream>>>(
        xs, dis, head, pay4, cst, Wout, bout, out);
}